// Round 4
// baseline (283.200 us; speedup 1.0000x reference)
//
#include <hip/hip_runtime.h>
#include <hip/hip_bf16.h>

typedef unsigned short ushort_t;
typedef unsigned int uint32;
typedef __attribute__((ext_vector_type(8))) short short8;
typedef __attribute__((ext_vector_type(4))) float f32x4;

static __device__ __forceinline__ ushort_t f2bf(float f) {
  uint32 u = __builtin_bit_cast(uint32, f);
  u += 0x7fffu + ((u >> 16) & 1u);   // round-to-nearest-even
  return (ushort_t)(u >> 16);
}

static __device__ __forceinline__ uint32 pack2bf(float x, float y) {
  __hip_bfloat162 h = __float22bfloat162_rn(make_float2(x, y));
  uint32 r;
  __builtin_memcpy(&r, &h, 4);
  return r;
}

static __device__ __forceinline__ void gload_lds16(const ushort_t* g, ushort_t* l) {
  __builtin_amdgcn_global_load_lds(
      (const __attribute__((address_space(1))) uint32*)g,
      (__attribute__((address_space(3))) uint32*)l, 16, 0, 0);
}

// ---------------------------------------------------------------------------
// prep: all weight fp32->bf16 conversions + bqc concat + Z zero + ctx zero,
// one launch. grid = 2049 blocks.
// ---------------------------------------------------------------------------
__global__ void prep_kernel(const float* __restrict__ Wq1, const float* __restrict__ Wq2,
                            const float* __restrict__ Wk1, const float* __restrict__ Wv1,
                            const float* __restrict__ Wk2, const float* __restrict__ Wv2,
                            const float* __restrict__ bq1, const float* __restrict__ bq2,
                            ushort_t* __restrict__ WqB, ushort_t* __restrict__ Wk1B,
                            ushort_t* __restrict__ Wv1B, ushort_t* __restrict__ Wk2B,
                            ushort_t* __restrict__ Wv2B, float* __restrict__ bqc,
                            float* __restrict__ Z, float* __restrict__ ctx) {
  int b = blockIdx.x, t = threadIdx.x;
  if (b < 1536) {
    int arr = b >> 8, i = (b & 255) * 256 + t;
    const float* s; ushort_t* d;
    switch (arr) {
      case 0: s = Wq1; d = WqB; break;
      case 1: s = Wq2; d = WqB + 262144; break;
      case 2: s = Wk1; d = Wk1B; break;
      case 3: s = Wv1; d = Wv1B; break;
      case 4: s = Wk2; d = Wk2B; break;
      default: s = Wv2; d = Wv2B; break;
    }
    float4 v = reinterpret_cast<const float4*>(s)[i];
    ushort4 u;
    u.x = f2bf(v.x); u.y = f2bf(v.y); u.z = f2bf(v.z); u.w = f2bf(v.w);
    reinterpret_cast<ushort4*>(d)[i] = u;
  } else if (b < 2048) {
    int i = (b - 1536) * 256 + t;                 // 512*256 float4 = 2 MB ctx
    reinterpret_cast<float4*>(ctx)[i] = make_float4(0.f, 0.f, 0.f, 0.f);
  } else {
    for (int i = t; i < 512; i += 256) { bqc[i] = bq1[i]; bqc[512 + i] = bq2[i]; }
    for (int i = t; i < 8192; i += 256) Z[i] = 0.f;
  }
}

// ---------------------------------------------------------------------------
// GEMM core, B via global_load_lds (bf16), A reg-staged from fp32 (a [+ pe])
// with on-the-fly bf16 conversion. 128x128 tile, 4 waves, BK=64.
// LDS: row-major 128 rows x 128B, XOR-swizzle byte ^= ((row&7)<<4).
// B gload_lds writes lane-linear, so B's global source is inverse-swizzled.
// ---------------------------------------------------------------------------
static __device__ __forceinline__ void gemm_core_f32A(
    const float* __restrict__ a, const float* __restrict__ pe,
    const ushort_t* __restrict__ Bt, int K, int mBase, int nBase,
    ushort_t* As, ushort_t* Bs, f32x4 acc[4][4]) {
  const int t = threadIdx.x;
  const int w = t >> 6, l = t & 63;
  const int l15 = l & 15, l4 = l >> 4;
  const int rowInSeg = l >> 3;
  const int srcOff = ((l & 7) ^ rowInSeg) << 3;
  const int wm = (w >> 1) * 64, wn = (w & 1) * 64;

  for (int k0 = 0; k0 < K; k0 += 64) {
    // B: async DMA to LDS (in flight during A conversion)
#pragma unroll
    for (int i = 0; i < 4; i++) {
      int seg = w * 4 + i;
      int row = seg * 8 + rowInSeg;
      gload_lds16(Bt + (size_t)(nBase + row) * K + k0 + srcOff, Bs + seg * 512);
    }
    // A: fp32 load (+pe), convert, swizzled ds_write
#pragma unroll
    for (int i = 0; i < 4; i++) {
      int u = i * 256 + t;
      int row = u >> 3, seg = u & 7;
      const float* src = a + (size_t)(mBase + row) * K + k0 + seg * 8;
      float4 v0 = *reinterpret_cast<const float4*>(src);
      float4 v1 = *reinterpret_cast<const float4*>(src + 4);
      if (pe != nullptr) {
        const float* ps = pe + (size_t)(mBase + row) * K + k0 + seg * 8;
        float4 p0 = *reinterpret_cast<const float4*>(ps);
        float4 p1 = *reinterpret_cast<const float4*>(ps + 4);
        v0.x += p0.x; v0.y += p0.y; v0.z += p0.z; v0.w += p0.w;
        v1.x += p1.x; v1.y += p1.y; v1.z += p1.z; v1.w += p1.w;
      }
      uint4 q;
      q.x = pack2bf(v0.x, v0.y);
      q.y = pack2bf(v0.z, v0.w);
      q.z = pack2bf(v1.x, v1.y);
      q.w = pack2bf(v1.z, v1.w);
      *reinterpret_cast<uint4*>(reinterpret_cast<char*>(As) + row * 128 +
                                ((seg * 16) ^ ((row & 7) << 4))) = q;
    }
    __syncthreads();
#pragma unroll
    for (int kk = 0; kk < 2; kk++) {
      short8 af[4], bfr[4];
      const int kb = kk * 64 + l4 * 16;
#pragma unroll
      for (int f = 0; f < 4; f++) {
        int rowA = wm + f * 16 + l15;
        af[f] = *reinterpret_cast<const short8*>(
            reinterpret_cast<const char*>(As) + rowA * 128 + (kb ^ ((rowA & 7) << 4)));
        int rowB = wn + f * 16 + l15;
        bfr[f] = *reinterpret_cast<const short8*>(
            reinterpret_cast<const char*>(Bs) + rowB * 128 + (kb ^ ((rowB & 7) << 4)));
      }
#pragma unroll
      for (int fm = 0; fm < 4; fm++)
#pragma unroll
        for (int fn = 0; fn < 4; fn++)
          acc[fm][fn] = __builtin_amdgcn_mfma_f32_16x16x32_bf16(af[fm], bfr[fn], acc[fm][fn], 0, 0, 0);
    }
    __syncthreads();
  }
}

// ---------------------------------------------------------------------------
// GEMM core, both operands bf16 via global_load_lds (used by G2).
// ---------------------------------------------------------------------------
static __device__ __forceinline__ void gemm_core_bf(
    const ushort_t* __restrict__ A, const ushort_t* __restrict__ Bt,
    int K, int mBase, int nBase, ushort_t* As, ushort_t* Bs, f32x4 acc[4][4]) {
  const int t = threadIdx.x;
  const int w = t >> 6, l = t & 63;
  const int l15 = l & 15, l4 = l >> 4;
  const int rowInSeg = l >> 3;
  const int srcOff = ((l & 7) ^ rowInSeg) << 3;
  const int wm = (w >> 1) * 64, wn = (w & 1) * 64;

  for (int k0 = 0; k0 < K; k0 += 64) {
#pragma unroll
    for (int i = 0; i < 4; i++) {
      int seg = w * 4 + i;
      int row = seg * 8 + rowInSeg;
      gload_lds16(A + (size_t)(mBase + row) * K + k0 + srcOff, As + seg * 512);
      gload_lds16(Bt + (size_t)(nBase + row) * K + k0 + srcOff, Bs + seg * 512);
    }
    __syncthreads();
#pragma unroll
    for (int kk = 0; kk < 2; kk++) {
      short8 af[4], bfr[4];
      const int kb = kk * 64 + l4 * 16;
#pragma unroll
      for (int f = 0; f < 4; f++) {
        int rowA = wm + f * 16 + l15;
        af[f] = *reinterpret_cast<const short8*>(
            reinterpret_cast<const char*>(As) + rowA * 128 + (kb ^ ((rowA & 7) << 4)));
        int rowB = wn + f * 16 + l15;
        bfr[f] = *reinterpret_cast<const short8*>(
            reinterpret_cast<const char*>(Bs) + rowB * 128 + (kb ^ ((rowB & 7) << 4)));
      }
#pragma unroll
      for (int fm = 0; fm < 4; fm++)
#pragma unroll
        for (int fn = 0; fn < 4; fn++)
          acc[fm][fn] = __builtin_amdgcn_mfma_f32_16x16x32_bf16(af[fm], bfr[fn], acc[fm][fn], 0, 0, 0);
    }
    __syncthreads();
  }
}

// ---------------------------------------------------------------------------
// G1: E = exp((f2+f2pe) @ WqB^T + bqc) -> bf16, column sums into Z.
// grid 2048 = 256 m-tiles x 8 n-tiles, XCD-chunked swizzle.
// ---------------------------------------------------------------------------
__global__ __launch_bounds__(256, 4)
void gemm_g1(const float* __restrict__ f2, const float* __restrict__ f2pe,
             const ushort_t* __restrict__ Bt, const float* __restrict__ bias,
             ushort_t* __restrict__ E, float* __restrict__ Z) {
  __shared__ ushort_t As[8192], Bs[8192];
  const int bid = blockIdx.x;
  const int swz = (bid & 7) * 256 + (bid >> 3);
  const int mBase = (swz >> 3) * 128, nBase = (swz & 7) * 128;
  const int t = threadIdx.x, w = t >> 6, lane = t & 63;
  const int l15 = lane & 15, l4 = lane >> 4;
  const int wm = (w >> 1) * 64, wn = (w & 1) * 64;

  f32x4 acc[4][4];
#pragma unroll
  for (int i = 0; i < 4; i++)
#pragma unroll
    for (int j = 0; j < 4; j++) acc[i][j] = (f32x4){0.f, 0.f, 0.f, 0.f};

  gemm_core_f32A(f2, f2pe, Bt, 512, mBase, nBase, As, Bs, acc);

  const int N = 1024;
#pragma unroll
  for (int fn = 0; fn < 4; fn++) {
    int col = nBase + wn + fn * 16 + l15;
    float bcol = bias[col];
    float csum = 0.f;
#pragma unroll
    for (int fm = 0; fm < 4; fm++) {
#pragma unroll
      for (int r = 0; r < 4; r++) {
        int row = mBase + wm + fm * 16 + l4 * 4 + r;
        float e = __expf(acc[fm][fn][r] + bcol);
        E[(size_t)row * N + col] = f2bf(e);
        csum += e;
      }
    }
    csum += __shfl_xor(csum, 16);
    csum += __shfl_xor(csum, 32);
    if (l4 == 0) atomicAdd(&Z[(mBase >> 12) * 1024 + col], csum);
  }
}

// ---------------------------------------------------------------------------
// KV quad: all four kv GEMMs (N=512, K=512), A from fp32 (+pe for k-ops),
// k-softmax fused in epilogue. grid 640, XCD-chunked swizzle.
// ---------------------------------------------------------------------------
__global__ __launch_bounds__(256, 4)
void kv_quad(const float* __restrict__ f3, const float* __restrict__ f3pe,
             const float* __restrict__ f4, const float* __restrict__ f4pe,
             const ushort_t* __restrict__ Wk1B, const ushort_t* __restrict__ Wv1B,
             const ushort_t* __restrict__ Wk2B, const ushort_t* __restrict__ Wv2B,
             const float* __restrict__ bk1, const float* __restrict__ bv1,
             const float* __restrict__ bk2, const float* __restrict__ bv2,
             ushort_t* __restrict__ ks3, ushort_t* __restrict__ v3,
             ushort_t* __restrict__ ks4, ushort_t* __restrict__ v4) {
  __shared__ ushort_t As[8192], Bs[8192];
  const int bid = blockIdx.x;
  const int id = (bid & 7) * 80 + (bid >> 3);    // 640 % 8 == 0: bijective
  const float* A; const float* Ape; const ushort_t* Bt; const float* bias;
  ushort_t* out; bool doSM; int loc;
  if (id < 256)      { A = f3; Ape = f3pe;    Bt = Wk1B; bias = bk1; out = ks3; doSM = true;  loc = id; }
  else if (id < 512) { A = f3; Ape = nullptr; Bt = Wv1B; bias = bv1; out = v3;  doSM = false; loc = id - 256; }
  else if (id < 576) { A = f4; Ape = f4pe;    Bt = Wk2B; bias = bk2; out = ks4; doSM = true;  loc = id - 512; }
  else               { A = f4; Ape = nullptr; Bt = Wv2B; bias = bv2; out = v4;  doSM = false; loc = id - 576; }
  const int nBase = (loc & 3) * 128, mBase = (loc >> 2) * 128;
  const int t = threadIdx.x, w = t >> 6, lane = t & 63;
  const int l15 = lane & 15, l4 = lane >> 4;
  const int wm = (w >> 1) * 64, wn = (w & 1) * 64;

  f32x4 acc[4][4];
#pragma unroll
  for (int i = 0; i < 4; i++)
#pragma unroll
    for (int j = 0; j < 4; j++) acc[i][j] = (f32x4){0.f, 0.f, 0.f, 0.f};

  gemm_core_f32A(A, Ape, Bt, 512, mBase, nBase, As, Bs, acc);

  const int N = 512;
  float bcol[4];
#pragma unroll
  for (int fn = 0; fn < 4; fn++) bcol[fn] = bias[nBase + wn + fn * 16 + l15];

  if (doSM) {
#pragma unroll
    for (int fm = 0; fm < 4; fm++) {
#pragma unroll
      for (int r = 0; r < 4; r++) {
        float x[4], m = -1e30f;
#pragma unroll
        for (int fn = 0; fn < 4; fn++) { x[fn] = acc[fm][fn][r] + bcol[fn]; m = fmaxf(m, x[fn]); }
        m = fmaxf(m, __shfl_xor(m, 1));
        m = fmaxf(m, __shfl_xor(m, 2));
        m = fmaxf(m, __shfl_xor(m, 4));
        m = fmaxf(m, __shfl_xor(m, 8));
        float s = 0.f;
#pragma unroll
        for (int fn = 0; fn < 4; fn++) { x[fn] = __expf(x[fn] - m); s += x[fn]; }
        s += __shfl_xor(s, 1);
        s += __shfl_xor(s, 2);
        s += __shfl_xor(s, 4);
        s += __shfl_xor(s, 8);
        float inv = 1.f / s;
        int row = mBase + wm + fm * 16 + l4 * 4 + r;
#pragma unroll
        for (int fn = 0; fn < 4; fn++)
          out[(size_t)row * N + nBase + wn + fn * 16 + l15] = f2bf(x[fn] * inv);
      }
    }
  } else {
#pragma unroll
    for (int fn = 0; fn < 4; fn++) {
      int col = nBase + wn + fn * 16 + l15;
#pragma unroll
      for (int fm = 0; fm < 4; fm++)
#pragma unroll
        for (int r = 0; r < 4; r++) {
          int row = mBase + wm + fm * 16 + l4 * 4 + r;
          out[(size_t)row * N + col] = f2bf(acc[fm][fn][r] + bcol[fn]);
        }
    }
  }
}

// ---------------------------------------------------------------------------
// G2: out_fp32 = E @ Mt(batch)^T + br.  grid 1024 = 256 m x 4 n, XCD swizzle.
// ---------------------------------------------------------------------------
__global__ __launch_bounds__(256, 4)
void gemm_g2(const ushort_t* __restrict__ E, const ushort_t* __restrict__ Mt,
             const float* __restrict__ bias, float* __restrict__ C) {
  __shared__ ushort_t As[8192], Bs[8192];
  const int bid = blockIdx.x;
  const int swz = (bid & 7) * 128 + (bid >> 3);
  const int tx = swz & 3, ty = swz >> 2;
  const int mBase = ty * 128, nBase = tx * 128;
  const ushort_t* Btb = Mt + (size_t)(ty >> 5) * 524288;
  const int t = threadIdx.x, w = t >> 6, lane = t & 63;
  const int l15 = lane & 15, l4 = lane >> 4;
  const int wm = (w >> 1) * 64, wn = (w & 1) * 64;

  f32x4 acc[4][4];
#pragma unroll
  for (int i = 0; i < 4; i++)
#pragma unroll
    for (int j = 0; j < 4; j++) acc[i][j] = (f32x4){0.f, 0.f, 0.f, 0.f};

  gemm_core_bf(E, Btb, 1024, mBase, nBase, As, Bs, acc);

  const int N = 512;
#pragma unroll
  for (int fn = 0; fn < 4; fn++) {
    int col = nBase + wn + fn * 16 + l15;
    float bcol = bias[col];
#pragma unroll
    for (int fm = 0; fm < 4; fm++)
#pragma unroll
      for (int r = 0; r < 4; r++) {
        int row = mBase + wm + fm * 16 + l4 * 4 + r;
        C[(size_t)row * N + col] = acc[fm][fn][r] + bcol;
      }
  }
}

// ---------------------------------------------------------------------------
// ctx[bh,d,e] += sum_{n in chunk} ks[b,n,h*64+d] * v[b,n,h*64+e]
// ---------------------------------------------------------------------------
__global__ __launch_bounds__(256)
void ctx_kernel(const ushort_t* __restrict__ ks, const ushort_t* __restrict__ v,
                float* __restrict__ ctxOut, int Nk, int nChunks) {
  __shared__ float ks_s[64][68];
  __shared__ float v_s[64][68];
  int bh = blockIdx.x / nChunks;
  int chunk = blockIdx.x - bh * nChunks;
  int b = bh >> 3, h = bh & 7;
  int t = threadIdx.x;
  int td = t & 15, te = t >> 4;
  float acc[4][4] = {};
  size_t rowBase = (size_t)b * Nk + chunk * 256;
  for (int n0 = 0; n0 < 256; n0 += 64) {
#pragma unroll
    for (int i = 0; i < 16; i++) {
      int idx = i * 256 + t;
      int n = idx >> 6, d = idx & 63;
      size_t g = (rowBase + n0 + n) * 512 + h * 64 + d;
      ks_s[n][d] = __builtin_bit_cast(float, (uint32)ks[g] << 16);
      v_s[n][d] = __builtin_bit_cast(float, (uint32)v[g] << 16);
    }
    __syncthreads();
#pragma unroll 8
    for (int n = 0; n < 64; n++) {
      float4 cv = *reinterpret_cast<const float4*>(&ks_s[n][td * 4]);
      float4 vv = *reinterpret_cast<const float4*>(&v_s[n][te * 4]);
      float ca[4] = {cv.x, cv.y, cv.z, cv.w};
      float va[4] = {vv.x, vv.y, vv.z, vv.w};
#pragma unroll
      for (int i = 0; i < 4; i++)
#pragma unroll
        for (int j = 0; j < 4; j++) acc[i][j] += ca[i] * va[j];
    }
    __syncthreads();
  }
  float* dst = ctxOut + (size_t)bh * 4096;
#pragma unroll
  for (int i = 0; i < 4; i++)
#pragma unroll
    for (int j = 0; j < 4; j++)
      atomicAdd(&dst[(td * 4 + i) * 64 + te * 4 + j], acc[i][j]);
}

// ---------------------------------------------------------------------------
// Fold: Mt[b][j][c] = (sum_e ctx[branch,b,h,d,e]*Wr[j, branch*512+h*64+e]) / Z[b,c]
// ---------------------------------------------------------------------------
__global__ __launch_bounds__(256)
void fold_kernel(const float* __restrict__ ctx, const float* __restrict__ Wr,
                 const float* __restrict__ Z, ushort_t* __restrict__ Mt) {
  __shared__ float ctxT[64][68];   // [e][d]
  __shared__ float wrT[64][68];    // [e][jl]
  __shared__ float zinv[64];
  int blk = blockIdx.x;
  int jc = blk & 7;
  int h = (blk >> 3) & 7;
  int branch = (blk >> 6) & 1;
  int b = blk >> 7;
  int t = threadIdx.x;
  int cbase = branch * 512 + h * 64;
  const float* csrc = ctx + (size_t)(branch * 64 + b * 8 + h) * 4096;
#pragma unroll
  for (int i = 0; i < 16; i++) {
    int idx = i * 256 + t;
    int d = idx >> 6, e = idx & 63;
    ctxT[e][d] = csrc[d * 64 + e];
  }
#pragma unroll
  for (int i = 0; i < 16; i++) {
    int idx = i * 256 + t;
    int jl = idx >> 6, e = idx & 63;
    wrT[e][jl] = Wr[(size_t)(jc * 64 + jl) * 1024 + cbase + e];
  }
  if (t < 64) zinv[t] = 1.0f / Z[b * 1024 + cbase + t];
  __syncthreads();
  int td = t & 15, tj = t >> 4;
  float acc[4][4] = {};   // [d_i][jj]
#pragma unroll 8
  for (int e = 0; e < 64; e++) {
    float4 cv = *reinterpret_cast<const float4*>(&ctxT[e][td * 4]);
    float4 wv = *reinterpret_cast<const float4*>(&wrT[e][tj * 4]);
    float ca[4] = {cv.x, cv.y, cv.z, cv.w};
    float wa[4] = {wv.x, wv.y, wv.z, wv.w};
#pragma unroll
    for (int i = 0; i < 4; i++)
#pragma unroll
      for (int jj = 0; jj < 4; jj++) acc[i][jj] += ca[i] * wa[jj];
  }
  float zi[4] = {zinv[td * 4], zinv[td * 4 + 1], zinv[td * 4 + 2], zinv[td * 4 + 3]};
#pragma unroll
  for (int jj = 0; jj < 4; jj++) {
    ushort4 u;
    u.x = f2bf(acc[0][jj] * zi[0]);
    u.y = f2bf(acc[1][jj] * zi[1]);
    u.z = f2bf(acc[2][jj] * zi[2]);
    u.w = f2bf(acc[3][jj] * zi[3]);
    *reinterpret_cast<ushort4*>(
        &Mt[(size_t)(b * 512 + jc * 64 + tj * 4 + jj) * 1024 + cbase + td * 4]) = u;
  }
}

// ---------------------------------------------------------------------------
extern "C" void kernel_launch(void* const* d_in, const int* in_sizes, int n_in,
                              void* d_out, int out_size, void* d_ws, size_t ws_size,
                              hipStream_t stream) {
  const float* f2 = (const float*)d_in[0];
  const float* f3 = (const float*)d_in[1];
  const float* f4 = (const float*)d_in[2];
  const float* f2pe = (const float*)d_in[3];
  const float* f3pe = (const float*)d_in[4];
  const float* f4pe = (const float*)d_in[5];
  const float* Wq1 = (const float*)d_in[6];
  const float* bq1 = (const float*)d_in[7];
  const float* Wk1 = (const float*)d_in[8];
  const float* bk1 = (const float*)d_in[9];
  const float* Wv1 = (const float*)d_in[10];
  const float* bv1 = (const float*)d_in[11];
  const float* Wq2 = (const float*)d_in[12];
  const float* bq2 = (const float*)d_in[13];
  const float* Wk2 = (const float*)d_in[14];
  const float* bk2 = (const float*)d_in[15];
  const float* Wv2 = (const float*)d_in[16];
  const float* bv2 = (const float*)d_in[17];
  const float* Wr = (const float*)d_in[18];
  const float* br = (const float*)d_in[19];

  char* ws = (char*)d_ws;
  // Region 0: E bf16 [32768,1024]
  ushort_t* E = (ushort_t*)(ws + 0);                       // 67,108,864 B
  // Region 1: ctx accumulators fp32
  char* R1 = ws + 67108864;
  float* ctx = (float*)(R1 + 10485760);                    // 2,097,152 B
  // Region 2: kv GEMM outputs (softmaxed k + v, bf16)
  char* R2 = ws + 100663296;
  ushort_t* ks3 = (ushort_t*)R2;
  ushort_t* v3b = (ushort_t*)(R2 + 8388608);
  ushort_t* ks4 = (ushort_t*)(R2 + 16777216);
  ushort_t* v4b = (ushort_t*)(R2 + 18874368);
  // Region 3: weights bf16, Mt, Z, bqcat
  char* R3 = ws + 121634816;
  ushort_t* WqB = (ushort_t*)R3;                           // 1,048,576
  ushort_t* Wk1B = (ushort_t*)(R3 + 1048576);
  ushort_t* Wv1B = (ushort_t*)(R3 + 1572864);
  ushort_t* Wk2B = (ushort_t*)(R3 + 2097152);
  ushort_t* Wv2B = (ushort_t*)(R3 + 2621440);
  ushort_t* Mt = (ushort_t*)(R3 + 3145728);                // 8,388,608
  float* Z = (float*)(R3 + 11534336);                      // 32,768
  float* bqc = (float*)(R3 + 11567104);                    // 4,096

  // ---- prep: weights->bf16, bqc, Z=0, ctx=0 (one launch) ----
  prep_kernel<<<2049, 256, 0, stream>>>(Wq1, Wq2, Wk1, Wv1, Wk2, Wv2, bq1, bq2,
                                        WqB, Wk1B, Wv1B, Wk2B, Wv2B, bqc, Z, ctx);

  // ---- G1: E = exp((f2+f2pe) @ WqB^T + bqc), Z colsums (A-prep fused) ----
  gemm_g1<<<2048, 256, 0, stream>>>(f2, f2pe, WqB, bqc, E, Z);

  // ---- all four kv GEMMs in one launch, A-prep + k-softmax fused ----
  kv_quad<<<640, 256, 0, stream>>>(f3, f3pe, f4, f4pe,
                                   Wk1B, Wv1B, Wk2B, Wv2B,
                                   bk1, bv1, bk2, bv2,
                                   ks3, v3b, ks4, v4b);

  // ---- ctx = ks^T v  per (b,h), chunked over n with atomic accumulation ----
  ctx_kernel<<<256, 256, 0, stream>>>(ks3, v3b, ctx, 1024, 4);
  ctx_kernel<<<64, 256, 0, stream>>>(ks4, v4b, ctx + 262144, 256, 1);

  // ---- fold ctx, Wr, 1/Z into per-batch Mt[b][j][c] ----
  fold_kernel<<<1024, 256, 0, stream>>>(ctx, Wr, Z, Mt);

  // ---- G2: out = E @ Mt^T + br  (per-batch Bt) ----
  gemm_g2<<<1024, 256, 0, stream>>>(E, Mt, br, (float*)d_out);
}

// Round 5
// 230.653 us; speedup vs baseline: 1.2278x; 1.2278x over previous
//
#include <hip/hip_runtime.h>

typedef unsigned short ushort_t;
typedef unsigned int uint32;
typedef __attribute__((ext_vector_type(8))) short short8;
typedef __attribute__((ext_vector_type(4))) float f32x4;

static __device__ __forceinline__ ushort_t f2bf(float f) {
  uint32 u = __builtin_bit_cast(uint32, f);
  u += 0x7fffu + ((u >> 16) & 1u);   // round-to-nearest-even
  return (ushort_t)(u >> 16);
}

static __device__ __forceinline__ void gload_lds16(const ushort_t* g, ushort_t* l) {
  __builtin_amdgcn_global_load_lds(
      (const __attribute__((address_space(1))) uint32*)g,
      (__attribute__((address_space(3))) uint32*)l, 16, 0, 0);
}

static __device__ __forceinline__ void addcvt4(const float* __restrict__ a,
                                               const float* __restrict__ b,
                                               ushort_t* __restrict__ o, int i) {
  float4 va = reinterpret_cast<const float4*>(a)[i];
  if (b != nullptr) {
    float4 vb = reinterpret_cast<const float4*>(b)[i];
    va.x += vb.x; va.y += vb.y; va.z += vb.z; va.w += vb.w;
  }
  ushort4 u;
  u.x = f2bf(va.x); u.y = f2bf(va.y); u.z = f2bf(va.z); u.w = f2bf(va.w);
  reinterpret_cast<ushort4*>(o)[i] = u;
}

// ---------------------------------------------------------------------------
// prep1: f2p = bf16(f2+f2pe), weights fp32->bf16, bqc concat, Z zero.
// grid = 17921 blocks. Runs before G1.
// ---------------------------------------------------------------------------
__global__ void prep1_kernel(const float* __restrict__ f2, const float* __restrict__ f2pe,
                             const float* __restrict__ Wq1, const float* __restrict__ Wq2,
                             const float* __restrict__ Wk1, const float* __restrict__ Wv1,
                             const float* __restrict__ Wk2, const float* __restrict__ Wv2,
                             const float* __restrict__ bq1, const float* __restrict__ bq2,
                             ushort_t* __restrict__ f2p, ushort_t* __restrict__ WqB,
                             ushort_t* __restrict__ Wk1B, ushort_t* __restrict__ Wv1B,
                             ushort_t* __restrict__ Wk2B, ushort_t* __restrict__ Wv2B,
                             float* __restrict__ bqc, float* __restrict__ Z) {
  int b = blockIdx.x, t = threadIdx.x;
  if (b < 16384) {
    addcvt4(f2, f2pe, f2p, b * 256 + t);
  } else if (b < 17920) {
    int u = b - 16384;
    int arr = u >> 8, i = (u & 255) * 256 + t;
    const float* s; ushort_t* d;
    switch (arr) {
      case 0: s = Wq1; d = WqB; break;
      case 1: s = Wq2; d = WqB + 262144; break;
      case 2: s = Wk1; d = Wk1B; break;
      case 3: s = Wv1; d = Wv1B; break;
      case 4: s = Wk2; d = Wk2B; break;
      default: s = Wv2; d = Wv2B; break;
    }
    addcvt4(s, nullptr, d, i);
  } else {
    for (int i = t; i < 512; i += 256) { bqc[i] = bq1[i]; bqc[512 + i] = bq2[i]; }
    for (int i = t; i < 8192; i += 256) Z[i] = 0.f;
  }
}

// ---------------------------------------------------------------------------
// prep2: kv GEMM inputs (bf16) + ctx zero. Runs after G1 (reuses f2p space).
// grid = 10752 blocks.
// ---------------------------------------------------------------------------
__global__ void prep2_kernel(const float* __restrict__ f3, const float* __restrict__ f3pe,
                             const float* __restrict__ f4, const float* __restrict__ f4pe,
                             ushort_t* __restrict__ f3p, ushort_t* __restrict__ f3b,
                             ushort_t* __restrict__ f4p, ushort_t* __restrict__ f4b,
                             float* __restrict__ ctx) {
  int b = blockIdx.x, t = threadIdx.x;
  if (b < 4096)       addcvt4(f3, f3pe, f3p, b * 256 + t);
  else if (b < 8192)  addcvt4(f3, nullptr, f3b, (b - 4096) * 256 + t);
  else if (b < 9216)  addcvt4(f4, f4pe, f4p, (b - 8192) * 256 + t);
  else if (b < 10240) addcvt4(f4, nullptr, f4b, (b - 9216) * 256 + t);
  else reinterpret_cast<float4*>(ctx)[(b - 10240) * 256 + t] = make_float4(0.f, 0.f, 0.f, 0.f);
}

// ---------------------------------------------------------------------------
// Shared GEMM core: 128x128 tile, 4 waves, BK=64, global_load_lds staging.
// LDS: row-major 128 x 128B, XOR-swizzle byte ^= ((row&7)<<4).
// gload_lds writes lane-linear, so the global SOURCE is inverse-swizzled.
// ---------------------------------------------------------------------------
static __device__ __forceinline__ void gemm_core(
    const ushort_t* __restrict__ A, const ushort_t* __restrict__ Bt,
    int K, int mBase, int nBase, ushort_t* As, ushort_t* Bs, f32x4 acc[4][4]) {
  const int t = threadIdx.x;
  const int w = t >> 6, l = t & 63;
  const int l15 = l & 15, l4 = l >> 4;
  const int rowInSeg = l >> 3;
  const int srcOff = ((l & 7) ^ rowInSeg) << 3;
  const int wm = (w >> 1) * 64, wn = (w & 1) * 64;

  for (int k0 = 0; k0 < K; k0 += 64) {
#pragma unroll
    for (int i = 0; i < 4; i++) {
      int seg = w * 4 + i;
      int row = seg * 8 + rowInSeg;
      gload_lds16(A + (size_t)(mBase + row) * K + k0 + srcOff, As + seg * 512);
      gload_lds16(Bt + (size_t)(nBase + row) * K + k0 + srcOff, Bs + seg * 512);
    }
    __syncthreads();
#pragma unroll
    for (int kk = 0; kk < 2; kk++) {
      short8 af[4], bfr[4];
      const int kb = kk * 64 + l4 * 16;
#pragma unroll
      for (int f = 0; f < 4; f++) {
        int rowA = wm + f * 16 + l15;
        af[f] = *reinterpret_cast<const short8*>(
            reinterpret_cast<const char*>(As) + rowA * 128 + (kb ^ ((rowA & 7) << 4)));
        int rowB = wn + f * 16 + l15;
        bfr[f] = *reinterpret_cast<const short8*>(
            reinterpret_cast<const char*>(Bs) + rowB * 128 + (kb ^ ((rowB & 7) << 4)));
      }
#pragma unroll
      for (int fm = 0; fm < 4; fm++)
#pragma unroll
        for (int fn = 0; fn < 4; fn++)
          acc[fm][fn] = __builtin_amdgcn_mfma_f32_16x16x32_bf16(af[fm], bfr[fn], acc[fm][fn], 0, 0, 0);
    }
    __syncthreads();
  }
}

// ---------------------------------------------------------------------------
// G1: E = exp(f2p @ WqB^T + bqc) -> bf16, column sums into Z.
// grid 2048 = 256 m-tiles x 8 n-tiles, XCD-chunked swizzle.
// ---------------------------------------------------------------------------
__global__ __launch_bounds__(256, 4)
void gemm_g1(const ushort_t* __restrict__ A, const ushort_t* __restrict__ Bt,
             const float* __restrict__ bias, ushort_t* __restrict__ E,
             float* __restrict__ Z) {
  __shared__ ushort_t As[8192], Bs[8192];
  const int bid = blockIdx.x;
  const int swz = (bid & 7) * 256 + (bid >> 3);
  const int mBase = (swz >> 3) * 128, nBase = (swz & 7) * 128;
  const int t = threadIdx.x, w = t >> 6, lane = t & 63;
  const int l15 = lane & 15, l4 = lane >> 4;
  const int wm = (w >> 1) * 64, wn = (w & 1) * 64;

  f32x4 acc[4][4];
#pragma unroll
  for (int i = 0; i < 4; i++)
#pragma unroll
    for (int j = 0; j < 4; j++) acc[i][j] = (f32x4){0.f, 0.f, 0.f, 0.f};

  gemm_core(A, Bt, 512, mBase, nBase, As, Bs, acc);

  const int N = 1024;
#pragma unroll
  for (int fn = 0; fn < 4; fn++) {
    int col = nBase + wn + fn * 16 + l15;
    float bcol = bias[col];
    float csum = 0.f;
#pragma unroll
    for (int fm = 0; fm < 4; fm++) {
#pragma unroll
      for (int r = 0; r < 4; r++) {
        int row = mBase + wm + fm * 16 + l4 * 4 + r;
        float e = __expf(acc[fm][fn][r] + bcol);
        E[(size_t)row * N + col] = f2bf(e);
        csum += e;
      }
    }
    csum += __shfl_xor(csum, 16);
    csum += __shfl_xor(csum, 32);
    if (l4 == 0) atomicAdd(&Z[(mBase >> 12) * 1024 + col], csum);
  }
}

// ---------------------------------------------------------------------------
// KV quad: all four kv GEMMs (N=512, K=512) in one 640-block launch,
// k-softmax fused in epilogue. XCD-chunked swizzle.
// ---------------------------------------------------------------------------
__global__ __launch_bounds__(256, 4)
void kv_quad(const ushort_t* __restrict__ f3p, const ushort_t* __restrict__ f3b,
             const ushort_t* __restrict__ f4p, const ushort_t* __restrict__ f4b,
             const ushort_t* __restrict__ Wk1B, const ushort_t* __restrict__ Wv1B,
             const ushort_t* __restrict__ Wk2B, const ushort_t* __restrict__ Wv2B,
             const float* __restrict__ bk1, const float* __restrict__ bv1,
             const float* __restrict__ bk2, const float* __restrict__ bv2,
             ushort_t* __restrict__ ks3, ushort_t* __restrict__ v3,
             ushort_t* __restrict__ ks4, ushort_t* __restrict__ v4) {
  __shared__ ushort_t As[8192], Bs[8192];
  const int bid = blockIdx.x;
  const int id = (bid & 7) * 80 + (bid >> 3);    // 640 % 8 == 0: bijective
  const ushort_t* A; const ushort_t* Bt; const float* bias; ushort_t* out;
  bool doSM; int loc;
  if (id < 256)      { A = f3p; Bt = Wk1B; bias = bk1; out = ks3; doSM = true;  loc = id; }
  else if (id < 512) { A = f3b; Bt = Wv1B; bias = bv1; out = v3;  doSM = false; loc = id - 256; }
  else if (id < 576) { A = f4p; Bt = Wk2B; bias = bk2; out = ks4; doSM = true;  loc = id - 512; }
  else               { A = f4b; Bt = Wv2B; bias = bv2; out = v4;  doSM = false; loc = id - 576; }
  const int nBase = (loc & 3) * 128, mBase = (loc >> 2) * 128;
  const int t = threadIdx.x, w = t >> 6, lane = t & 63;
  const int l15 = lane & 15, l4 = lane >> 4;
  const int wm = (w >> 1) * 64, wn = (w & 1) * 64;

  f32x4 acc[4][4];
#pragma unroll
  for (int i = 0; i < 4; i++)
#pragma unroll
    for (int j = 0; j < 4; j++) acc[i][j] = (f32x4){0.f, 0.f, 0.f, 0.f};

  gemm_core(A, Bt, 512, mBase, nBase, As, Bs, acc);

  const int N = 512;
  float bcol[4];
#pragma unroll
  for (int fn = 0; fn < 4; fn++) bcol[fn] = bias[nBase + wn + fn * 16 + l15];

  if (doSM) {
#pragma unroll
    for (int fm = 0; fm < 4; fm++) {
#pragma unroll
      for (int r = 0; r < 4; r++) {
        float x[4], m = -1e30f;
#pragma unroll
        for (int fn = 0; fn < 4; fn++) { x[fn] = acc[fm][fn][r] + bcol[fn]; m = fmaxf(m, x[fn]); }
        m = fmaxf(m, __shfl_xor(m, 1));
        m = fmaxf(m, __shfl_xor(m, 2));
        m = fmaxf(m, __shfl_xor(m, 4));
        m = fmaxf(m, __shfl_xor(m, 8));
        float s = 0.f;
#pragma unroll
        for (int fn = 0; fn < 4; fn++) { x[fn] = __expf(x[fn] - m); s += x[fn]; }
        s += __shfl_xor(s, 1);
        s += __shfl_xor(s, 2);
        s += __shfl_xor(s, 4);
        s += __shfl_xor(s, 8);
        float inv = 1.f / s;
        int row = mBase + wm + fm * 16 + l4 * 4 + r;
#pragma unroll
        for (int fn = 0; fn < 4; fn++)
          out[(size_t)row * N + nBase + wn + fn * 16 + l15] = f2bf(x[fn] * inv);
      }
    }
  } else {
#pragma unroll
    for (int fn = 0; fn < 4; fn++) {
      int col = nBase + wn + fn * 16 + l15;
#pragma unroll
      for (int fm = 0; fm < 4; fm++)
#pragma unroll
        for (int r = 0; r < 4; r++) {
          int row = mBase + wm + fm * 16 + l4 * 4 + r;
          out[(size_t)row * N + col] = f2bf(acc[fm][fn][r] + bcol[fn]);
        }
    }
  }
}

// ---------------------------------------------------------------------------
// G2: out_fp32 = E @ Mt(batch)^T + br.  grid 1024 = 256 m x 4 n, XCD swizzle.
// ---------------------------------------------------------------------------
__global__ __launch_bounds__(256, 4)
void gemm_g2(const ushort_t* __restrict__ E, const ushort_t* __restrict__ Mt,
             const float* __restrict__ bias, float* __restrict__ C) {
  __shared__ ushort_t As[8192], Bs[8192];
  const int bid = blockIdx.x;
  const int swz = (bid & 7) * 128 + (bid >> 3);
  const int tx = swz & 3, ty = swz >> 2;
  const int mBase = ty * 128, nBase = tx * 128;
  const ushort_t* Btb = Mt + (size_t)(ty >> 5) * 524288;
  const int t = threadIdx.x, w = t >> 6, lane = t & 63;
  const int l15 = lane & 15, l4 = lane >> 4;
  const int wm = (w >> 1) * 64, wn = (w & 1) * 64;

  f32x4 acc[4][4];
#pragma unroll
  for (int i = 0; i < 4; i++)
#pragma unroll
    for (int j = 0; j < 4; j++) acc[i][j] = (f32x4){0.f, 0.f, 0.f, 0.f};

  gemm_core(E, Btb, 1024, mBase, nBase, As, Bs, acc);

  const int N = 512;
#pragma unroll
  for (int fn = 0; fn < 4; fn++) {
    int col = nBase + wn + fn * 16 + l15;
    float bcol = bias[col];
#pragma unroll
    for (int fm = 0; fm < 4; fm++)
#pragma unroll
      for (int r = 0; r < 4; r++) {
        int row = mBase + wm + fm * 16 + l4 * 4 + r;
        C[(size_t)row * N + col] = acc[fm][fn][r] + bcol;
      }
  }
}

// ---------------------------------------------------------------------------
// ctx[bh,d,e] += sum_{n in chunk} ks[b,n,h*64+d] * v[b,n,h*64+e]
// ---------------------------------------------------------------------------
__global__ __launch_bounds__(256)
void ctx_kernel(const ushort_t* __restrict__ ks, const ushort_t* __restrict__ v,
                float* __restrict__ ctxOut, int Nk, int nChunks) {
  __shared__ float ks_s[64][68];
  __shared__ float v_s[64][68];
  int bh = blockIdx.x / nChunks;
  int chunk = blockIdx.x - bh * nChunks;
  int b = bh >> 3, h = bh & 7;
  int t = threadIdx.x;
  int td = t & 15, te = t >> 4;
  float acc[4][4] = {};
  size_t rowBase = (size_t)b * Nk + chunk * 256;
  for (int n0 = 0; n0 < 256; n0 += 64) {
#pragma unroll
    for (int i = 0; i < 16; i++) {
      int idx = i * 256 + t;
      int n = idx >> 6, d = idx & 63;
      size_t g = (rowBase + n0 + n) * 512 + h * 64 + d;
      ks_s[n][d] = __builtin_bit_cast(float, (uint32)ks[g] << 16);
      v_s[n][d] = __builtin_bit_cast(float, (uint32)v[g] << 16);
    }
    __syncthreads();
#pragma unroll 8
    for (int n = 0; n < 64; n++) {
      float4 cv = *reinterpret_cast<const float4*>(&ks_s[n][td * 4]);
      float4 vv = *reinterpret_cast<const float4*>(&v_s[n][te * 4]);
      float ca[4] = {cv.x, cv.y, cv.z, cv.w};
      float va[4] = {vv.x, vv.y, vv.z, vv.w};
#pragma unroll
      for (int i = 0; i < 4; i++)
#pragma unroll
        for (int j = 0; j < 4; j++) acc[i][j] += ca[i] * va[j];
    }
    __syncthreads();
  }
  float* dst = ctxOut + (size_t)bh * 4096;
#pragma unroll
  for (int i = 0; i < 4; i++)
#pragma unroll
    for (int j = 0; j < 4; j++)
      atomicAdd(&dst[(td * 4 + i) * 64 + te * 4 + j], acc[i][j]);
}

// ---------------------------------------------------------------------------
// Fold: Mt[b][j][c] = (sum_e ctx[branch,b,h,d,e]*Wr[j, branch*512+h*64+e]) / Z[b,c]
// ---------------------------------------------------------------------------
__global__ __launch_bounds__(256)
void fold_kernel(const float* __restrict__ ctx, const float* __restrict__ Wr,
                 const float* __restrict__ Z, ushort_t* __restrict__ Mt) {
  __shared__ float ctxT[64][68];   // [e][d]
  __shared__ float wrT[64][68];    // [e][jl]
  __shared__ float zinv[64];
  int blk = blockIdx.x;
  int jc = blk & 7;
  int h = (blk >> 3) & 7;
  int branch = (blk >> 6) & 1;
  int b = blk >> 7;
  int t = threadIdx.x;
  int cbase = branch * 512 + h * 64;
  const float* csrc = ctx + (size_t)(branch * 64 + b * 8 + h) * 4096;
#pragma unroll
  for (int i = 0; i < 16; i++) {
    int idx = i * 256 + t;
    int d = idx >> 6, e = idx & 63;
    ctxT[e][d] = csrc[d * 64 + e];
  }
#pragma unroll
  for (int i = 0; i < 16; i++) {
    int idx = i * 256 + t;
    int jl = idx >> 6, e = idx & 63;
    wrT[e][jl] = Wr[(size_t)(jc * 64 + jl) * 1024 + cbase + e];
  }
  if (t < 64) zinv[t] = 1.0f / Z[b * 1024 + cbase + t];
  __syncthreads();
  int td = t & 15, tj = t >> 4;
  float acc[4][4] = {};   // [d_i][jj]
#pragma unroll 8
  for (int e = 0; e < 64; e++) {
    float4 cv = *reinterpret_cast<const float4*>(&ctxT[e][td * 4]);
    float4 wv = *reinterpret_cast<const float4*>(&wrT[e][tj * 4]);
    float ca[4] = {cv.x, cv.y, cv.z, cv.w};
    float wa[4] = {wv.x, wv.y, wv.z, wv.w};
#pragma unroll
    for (int i = 0; i < 4; i++)
#pragma unroll
      for (int jj = 0; jj < 4; jj++) acc[i][jj] += ca[i] * wa[jj];
  }
  float zi[4] = {zinv[td * 4], zinv[td * 4 + 1], zinv[td * 4 + 2], zinv[td * 4 + 3]};
#pragma unroll
  for (int jj = 0; jj < 4; jj++) {
    ushort4 u;
    u.x = f2bf(acc[0][jj] * zi[0]);
    u.y = f2bf(acc[1][jj] * zi[1]);
    u.z = f2bf(acc[2][jj] * zi[2]);
    u.w = f2bf(acc[3][jj] * zi[3]);
    *reinterpret_cast<ushort4*>(
        &Mt[(size_t)(b * 512 + jc * 64 + tj * 4 + jj) * 1024 + cbase + td * 4]) = u;
  }
}

// ---------------------------------------------------------------------------
extern "C" void kernel_launch(void* const* d_in, const int* in_sizes, int n_in,
                              void* d_out, int out_size, void* d_ws, size_t ws_size,
                              hipStream_t stream) {
  const float* f2 = (const float*)d_in[0];
  const float* f3 = (const float*)d_in[1];
  const float* f4 = (const float*)d_in[2];
  const float* f2pe = (const float*)d_in[3];
  const float* f3pe = (const float*)d_in[4];
  const float* f4pe = (const float*)d_in[5];
  const float* Wq1 = (const float*)d_in[6];
  const float* bq1 = (const float*)d_in[7];
  const float* Wk1 = (const float*)d_in[8];
  const float* bk1 = (const float*)d_in[9];
  const float* Wv1 = (const float*)d_in[10];
  const float* bv1 = (const float*)d_in[11];
  const float* Wq2 = (const float*)d_in[12];
  const float* bq2 = (const float*)d_in[13];
  const float* Wk2 = (const float*)d_in[14];
  const float* bk2 = (const float*)d_in[15];
  const float* Wv2 = (const float*)d_in[16];
  const float* bv2 = (const float*)d_in[17];
  const float* Wr = (const float*)d_in[18];
  const float* br = (const float*)d_in[19];

  char* ws = (char*)d_ws;
  // Region 0: E bf16 [32768,1024]
  ushort_t* E = (ushort_t*)(ws + 0);                       // 67,108,864 B
  // Region 1: f2p (live prep1->g1), then reused by prep2 outputs (after g1)
  char* R1 = ws + 67108864;                                // 33,554,432 B
  ushort_t* f2p = (ushort_t*)R1;
  ushort_t* f3p = (ushort_t*)R1;                           // 8,388,608
  ushort_t* f3b = (ushort_t*)(R1 + 8388608);               // 8,388,608
  ushort_t* f4p = (ushort_t*)(R1 + 16777216);              // 2,097,152
  ushort_t* f4b = (ushort_t*)(R1 + 18874368);              // 2,097,152
  float* ctx = (float*)(R1 + 20971520);                    // 2,097,152
  // Region 2: kv GEMM outputs (softmaxed k + v, bf16)
  char* R2 = ws + 100663296;
  ushort_t* ks3 = (ushort_t*)R2;
  ushort_t* v3b = (ushort_t*)(R2 + 8388608);
  ushort_t* ks4 = (ushort_t*)(R2 + 16777216);
  ushort_t* v4b = (ushort_t*)(R2 + 18874368);
  // Region 3: weights bf16, Mt, Z, bqcat
  char* R3 = ws + 121634816;
  ushort_t* WqB = (ushort_t*)R3;                           // 1,048,576
  ushort_t* Wk1B = (ushort_t*)(R3 + 1048576);
  ushort_t* Wv1B = (ushort_t*)(R3 + 1572864);
  ushort_t* Wk2B = (ushort_t*)(R3 + 2097152);
  ushort_t* Wv2B = (ushort_t*)(R3 + 2621440);
  ushort_t* Mt = (ushort_t*)(R3 + 3145728);                // 8,388,608
  float* Z = (float*)(R3 + 11534336);                      // 32,768
  float* bqc = (float*)(R3 + 11567104);                    // 4,096

  // ---- prep1: f2p, weights->bf16, bqc, Z=0 ----
  prep1_kernel<<<17921, 256, 0, stream>>>(f2, f2pe, Wq1, Wq2, Wk1, Wv1, Wk2, Wv2,
                                          bq1, bq2, f2p, WqB, Wk1B, Wv1B, Wk2B,
                                          Wv2B, bqc, Z);

  // ---- G1: E = exp(f2p @ WqB^T + bqc), Z colsums ----
  gemm_g1<<<2048, 256, 0, stream>>>(f2p, WqB, bqc, E, Z);

  // ---- prep2: kv inputs + ctx zero (reuses f2p space, dead after g1) ----
  prep2_kernel<<<10752, 256, 0, stream>>>(f3, f3pe, f4, f4pe, f3p, f3b, f4p, f4b, ctx);

  // ---- all four kv GEMMs in one launch, k-softmax fused ----
  kv_quad<<<640, 256, 0, stream>>>(f3p, f3b, f4p, f4b,
                                   Wk1B, Wv1B, Wk2B, Wv2B,
                                   bk1, bv1, bk2, bv2,
                                   ks3, v3b, ks4, v4b);

  // ---- ctx = ks^T v  per (b,h), chunked over n with atomic accumulation ----
  ctx_kernel<<<256, 256, 0, stream>>>(ks3, v3b, ctx, 1024, 4);
  ctx_kernel<<<64, 256, 0, stream>>>(ks4, v4b, ctx + 262144, 256, 1);

  // ---- fold ctx, Wr, 1/Z into per-batch Mt[b][j][c] ----
  fold_kernel<<<1024, 256, 0, stream>>>(ctx, Wr, Z, Mt);

  // ---- G2: out = E @ Mt^T + br  (per-batch Bt) ----
  gemm_g2<<<1024, 256, 0, stream>>>(E, Mt, br, (float*)d_out);
}